// Round 9
// baseline (604.995 us; speedup 1.0000x reference)
//
#include <hip/hip_runtime.h>
#include <hip/hip_cooperative_groups.h>

namespace cg = cooperative_groups;

#define D 64          // node/edge feature dim
#define HID 128       // hidden dim
#define MLPB 1024     // MLP block size (16 waves)
#define WPB 16        // waves per MLP block
#define NB 8          // nodes per wave-batch
#define CAP 96        // elist slots per node (mean degree 32; Poisson tail ~0)
#define WIN_SHIFT 12  // 4096 nodes per place-window -> ~1.5MB elist window

typedef unsigned short ush;

// bf16 round-to-nearest-even (finite normals)
__device__ __forceinline__ ush f2bf(float f)
{
    unsigned u = __float_as_uint(f);
    return (ush)((u + 0x7FFF + ((u >> 16) & 1)) >> 16);
}
__device__ __forceinline__ float bf_lo(unsigned p) { return __uint_as_float(p << 16); }
__device__ __forceinline__ float bf_hi(unsigned p) { return __uint_as_float(p & 0xFFFF0000u); }

// ---------------------------------------------------------------------------
// Index dtype: reference says int64, harness may deliver int32. Probe high
// words of the first 64 pairs: int64 -> all zero (ids < 50000); int32 ->
// random node ids, P(all zero) ~ (2e-5)^64 ~ 0. Deterministic.
// ---------------------------------------------------------------------------
__device__ __forceinline__ bool detect_i64(const int* __restrict__ eidx, int lane)
{
    int probe = eidx[2 * lane + 1];
    return (__ballot(probe == 0) == ~0ULL);
}

// ---------------------------------------------------------------------------
// Fused aggregate pipeline (cooperative): decode+zero -> windowed place ->
// gather -> overflow. Phase bodies identical to the R8 standalone kernels;
// grid.sync() replaces kernel boundaries (removes 3 launch gaps).
// ---------------------------------------------------------------------------
__global__ __launch_bounds__(256)
void fused_agg(const int* __restrict__ eidx, ush* __restrict__ nid,
               int* __restrict__ zbase, int* __restrict__ counts,
               int* __restrict__ elist, int* __restrict__ ovf_cnt,
               int2* __restrict__ ovf, const float* __restrict__ x_edge,
               float* __restrict__ agg, int n_edges, int n_nodes, int u16_ok)
{
    cg::grid_group grid = cg::this_grid();
    const int E2 = 2 * n_edges;
    const int tid = blockIdx.x * 256 + threadIdx.x;
    const int nthreads = gridDim.x * 256;
    const bool is64 = detect_i64(eidx, threadIdx.x & 63);

    // ---- phase 0: decode u16 nid + zero counts/ovf_cnt ----
    if (u16_ok) {
        for (int t = tid; t < E2; t += nthreads)
            nid[t] = (ush)(is64 ? eidx[2 * (size_t)t] : eidx[t]);
    }
    for (int t = tid; t < n_nodes + 2; t += nthreads) zbase[t] = 0;
    grid.sync();

    // ---- phase 1: windowed fixed-capacity place ----
    const int nwin = (n_nodes + (1 << WIN_SHIFT) - 1) >> WIN_SHIFT;
    for (int wi = 0; wi < nwin; ++wi) {
        const int lo = wi << WIN_SHIFT;
        const int hi = lo + (1 << WIN_SHIFT);
        for (int t = tid; t < E2; t += nthreads) {
            int idx = u16_ok ? (int)nid[t]
                             : (is64 ? eidx[2 * (size_t)t] : eidx[t]);
            if (idx >= lo && idx < hi) {
                int eid = (t < n_edges) ? t : t - n_edges;
                int c = atomicAdd(&counts[idx], 1);
                if (c < CAP) elist[(size_t)idx * CAP + c] = eid;
                else {
                    int p = atomicAdd(ovf_cnt, 1);
                    ovf[p] = make_int2(idx, eid);
                }
            }
        }
        // no sync needed between windows: disjoint count/elist ranges
    }
    grid.sync();

    // ---- phase 2: gather (one wave per node, R6-proven 4-deep ILP) ----
    {
        const int lane = threadIdx.x & 63;
        const int sub = lane >> 4;       // row slot 0..3
        const int q   = lane & 15;       // float4 index within 256B row
        const float4* __restrict__ xe4 = (const float4*)x_edge;
        const int wave0 = tid >> 6;
        const int nwaves = nthreads >> 6;

        for (int w = wave0; w < n_nodes; w += nwaves) {
            int cnt = counts[w]; if (cnt > CAP) cnt = CAP;
            const int beg = w * CAP, end = beg + cnt;
            float4 acc = make_float4(0.f, 0.f, 0.f, 0.f);

            int i = beg + sub;
            for (; i + 12 < end; i += 16) {
                int e0 = elist[i];
                int e1 = elist[i + 4];
                int e2 = elist[i + 8];
                int e3 = elist[i + 12];
                float4 v0 = xe4[(size_t)e0 * 16 + q];
                float4 v1 = xe4[(size_t)e1 * 16 + q];
                float4 v2 = xe4[(size_t)e2 * 16 + q];
                float4 v3 = xe4[(size_t)e3 * 16 + q];
                acc.x += (v0.x + v1.x) + (v2.x + v3.x);
                acc.y += (v0.y + v1.y) + (v2.y + v3.y);
                acc.z += (v0.z + v1.z) + (v2.z + v3.z);
                acc.w += (v0.w + v1.w) + (v2.w + v3.w);
            }
            for (; i < end; i += 4) {
                float4 v = xe4[(size_t)elist[i] * 16 + q];
                acc.x += v.x; acc.y += v.y; acc.z += v.z; acc.w += v.w;
            }

            #pragma unroll
            for (int m = 16; m < 64; m <<= 1) {
                acc.x += __shfl_xor(acc.x, m);
                acc.y += __shfl_xor(acc.y, m);
                acc.z += __shfl_xor(acc.z, m);
                acc.w += __shfl_xor(acc.w, m);
            }
            if (sub == 0)
                ((float4*)agg)[(size_t)w * 16 + q] = acc;
        }
    }
    grid.sync();

    // ---- phase 3: overflow cleanup (typically 0 entries) ----
    {
        const int n = *ovf_cnt;
        if (n > 0) {
            const int lane = threadIdx.x & 63;
            const int wave0 = tid >> 6;
            const int nwaves = nthreads >> 6;
            for (int i = wave0; i < n; i += nwaves) {
                int2 p = ovf[i];
                float v = x_edge[(size_t)p.y * D + lane];
                unsafeAtomicAdd(&agg[(size_t)p.x * D + lane], v);
            }
        }
    }
}

// ---------------------------------------------------------------------------
// Standalone fallback kernels (non-cooperative path) — R8-proven.
// ---------------------------------------------------------------------------
__global__ __launch_bounds__(256)
void p0_nid(const int* __restrict__ eidx, ush* __restrict__ nid,
            int* __restrict__ counts, int n_zero, int n_edges)
{
    const int t = blockIdx.x * 256 + threadIdx.x;
    const bool is64 = detect_i64(eidx, threadIdx.x & 63);
    const int E2 = 2 * n_edges;
    if (t < E2) nid[t] = (ush)(is64 ? eidx[2 * (size_t)t] : eidx[t]);
    if (t < n_zero) counts[t] = 0;
}

__global__ __launch_bounds__(256)
void p1_place16(const ush* __restrict__ nid, int* __restrict__ counts,
                int* __restrict__ elist, int* __restrict__ ovf_cnt,
                int2* __restrict__ ovf, int n_edges)
{
    const int lo = blockIdx.y << WIN_SHIFT;
    const int hi = lo + (1 << WIN_SHIFT);
    const int E2 = 2 * n_edges;
    const int stride = gridDim.x * 256;
    for (int t = blockIdx.x * 256 + threadIdx.x; t < E2; t += stride) {
        int idx = nid[t];
        if (idx >= lo && idx < hi) {
            int eid = (t < n_edges) ? t : t - n_edges;
            int c = atomicAdd(&counts[idx], 1);
            if (c < CAP) elist[(size_t)idx * CAP + c] = eid;
            else {
                int p = atomicAdd(ovf_cnt, 1);
                ovf[p] = make_int2(idx, eid);
            }
        }
    }
}

__global__ __launch_bounds__(256)
void p1_place(const int* __restrict__ eidx, int* __restrict__ counts,
              int* __restrict__ elist, int* __restrict__ ovf_cnt,
              int2* __restrict__ ovf, int n_edges)
{
    const int lo = blockIdx.y << WIN_SHIFT;
    const int hi = lo + (1 << WIN_SHIFT);
    const int E2 = 2 * n_edges;
    const bool is64 = detect_i64(eidx, threadIdx.x & 63);
    const int stride = gridDim.x * 256;
    for (int t = blockIdx.x * 256 + threadIdx.x; t < E2; t += stride) {
        int idx = is64 ? eidx[2 * (size_t)t] : eidx[t];
        if (idx >= lo && idx < hi) {
            int eid = (t < n_edges) ? t : t - n_edges;
            int c = atomicAdd(&counts[idx], 1);
            if (c < CAP) elist[(size_t)idx * CAP + c] = eid;
            else {
                int p = atomicAdd(ovf_cnt, 1);
                ovf[p] = make_int2(idx, eid);
            }
        }
    }
}

__global__ __launch_bounds__(256)
void p2_gather(const float* __restrict__ x_edge, const int* __restrict__ counts,
               const int* __restrict__ elist, float* __restrict__ agg, int n_nodes)
{
    const int w = (blockIdx.x * 256 + threadIdx.x) >> 6;
    if (w >= n_nodes) return;
    const int lane = threadIdx.x & 63;
    const int sub = lane >> 4;
    const int q   = lane & 15;
    const float4* __restrict__ xe4 = (const float4*)x_edge;

    int cnt = counts[w]; if (cnt > CAP) cnt = CAP;
    const int beg = w * CAP, end = beg + cnt;
    float4 acc = make_float4(0.f, 0.f, 0.f, 0.f);

    int i = beg + sub;
    for (; i + 12 < end; i += 16) {
        int e0 = elist[i];
        int e1 = elist[i + 4];
        int e2 = elist[i + 8];
        int e3 = elist[i + 12];
        float4 v0 = xe4[(size_t)e0 * 16 + q];
        float4 v1 = xe4[(size_t)e1 * 16 + q];
        float4 v2 = xe4[(size_t)e2 * 16 + q];
        float4 v3 = xe4[(size_t)e3 * 16 + q];
        acc.x += (v0.x + v1.x) + (v2.x + v3.x);
        acc.y += (v0.y + v1.y) + (v2.y + v3.y);
        acc.z += (v0.z + v1.z) + (v2.z + v3.z);
        acc.w += (v0.w + v1.w) + (v2.w + v3.w);
    }
    for (; i < end; i += 4) {
        float4 v = xe4[(size_t)elist[i] * 16 + q];
        acc.x += v.x; acc.y += v.y; acc.z += v.z; acc.w += v.w;
    }
    #pragma unroll
    for (int m = 16; m < 64; m <<= 1) {
        acc.x += __shfl_xor(acc.x, m);
        acc.y += __shfl_xor(acc.y, m);
        acc.z += __shfl_xor(acc.z, m);
        acc.w += __shfl_xor(acc.w, m);
    }
    if (sub == 0)
        ((float4*)agg)[(size_t)w * 16 + q] = acc;
}

__global__ __launch_bounds__(256)
void p3_ovf(const float* __restrict__ x_edge, const int* __restrict__ ovf_cnt,
            const int2* __restrict__ ovf, float* __restrict__ agg)
{
    const int n = *ovf_cnt;
    const int lane = threadIdx.x & 63;
    const int wv = (blockIdx.x * 256 + threadIdx.x) >> 6;
    const int nw = gridDim.x * 4;
    for (int i = wv; i < n; i += nw) {
        int2 p = ovf[i];
        float v = x_edge[(size_t)p.y * D + lane];
        unsafeAtomicAdd(&agg[(size_t)p.x * D + lane], v);
    }
}

// ---------- fallback atomic scatter (tiny ws) ------------------------------
__global__ __launch_bounds__(256)
void nb_scatter(const float* __restrict__ x_edge, const int* __restrict__ eidx,
                float* __restrict__ agg, int n_edges)
{
    long long t = (long long)blockIdx.x * 256 + threadIdx.x;
    int e = (int)(t >> 6);
    if (e >= n_edges) return;
    int d = (int)(t & 63);
    bool is64 = detect_i64(eidx, threadIdx.x & 63);
    int s, dd;
    if (is64) {
        s  = eidx[2 * (size_t)e];
        dd = eidx[2 * ((size_t)n_edges + (size_t)e)];
    } else {
        s  = eidx[e];
        dd = eidx[n_edges + e];
    }
    float v = x_edge[(size_t)e * D + d];
    unsafeAtomicAdd(&agg[(size_t)s * D + d], v);
    unsafeAtomicAdd(&agg[(size_t)dd * D + d], v);
}

// ---------------------------------------------------------------------------
// MLP: out[n] = relu(concat(x_node[n], agg[n]) @ W1 + b1) @ W2 + b2
// NB=8 nodes per wave-batch; W1 as float2 pairs (b64 -> 16 FMAs); W2 bf16-
// packed (b32 -> 32 FMAs); s_buf inputs/hidden overlaid. LDS ~145KB.
// ---------------------------------------------------------------------------
__global__ __launch_bounds__(MLPB, 1)
void p4_mlp(const float* __restrict__ x_node, const float* __restrict__ agg,
            const float* __restrict__ W1, const float* __restrict__ b1,
            const float* __restrict__ W2, const float* __restrict__ b2,
            float* __restrict__ out, int n_nodes)
{
    __shared__ float2   sW1p[HID * 64];        // 64 KB
    __shared__ unsigned sW2p[64 * 64];         // 16 KB
    __shared__ float    sb1[HID];
    __shared__ float    sb2[D];
    __shared__ float4   s_buf[WPB][128][2];    // 64 KB

    {
        for (int t = threadIdx.x; t < HID * 64; t += MLPB) {
            int k = t >> 6, j = t & 63;
            sW1p[t] = make_float2(W1[k * HID + j], W1[k * HID + 64 + j]);
        }
        for (int t = threadIdx.x; t < 64 * 64; t += MLPB) {
            int q = t >> 6, j = t & 63;
            unsigned lo = f2bf(W2[(2 * q) * D + j]);
            unsigned hi = f2bf(W2[(2 * q + 1) * D + j]);
            sW2p[t] = lo | (hi << 16);
        }
        if (threadIdx.x < 128) sb1[threadIdx.x] = b1[threadIdx.x];
        else if (threadIdx.x < 192) sb2[threadIdx.x - 128] = b2[threadIdx.x - 128];
    }
    __syncthreads();

    const int wave = threadIdx.x >> 6;
    const int lane = threadIdx.x & 63;
    const int group = blockIdx.x * WPB + wave;
    const int ngroups = gridDim.x * WPB;
    const int nbatches = (n_nodes + NB - 1) / NB;

    const float bh0 = sb1[lane], bh1 = sb1[64 + lane];
    const float bo  = sb2[lane];

    for (int g = group; g < nbatches; g += ngroups) {
        const int n0 = g * NB;

        float vx[NB], va[NB];
        #pragma unroll
        for (int b = 0; b < NB; ++b) {
            const int n = n0 + b;
            const bool ok = (n < n_nodes);
            vx[b] = ok ? x_node[(size_t)n * D + lane] : 0.f;
            va[b] = ok ? agg[(size_t)n * D + lane] : 0.f;
        }
        s_buf[wave][lane][0]      = make_float4(vx[0], vx[1], vx[2], vx[3]);
        s_buf[wave][lane][1]      = make_float4(vx[4], vx[5], vx[6], vx[7]);
        s_buf[wave][64 + lane][0] = make_float4(va[0], va[1], va[2], va[3]);
        s_buf[wave][64 + lane][1] = make_float4(va[4], va[5], va[6], va[7]);
        __builtin_amdgcn_wave_barrier();

        float a0[NB], a1[NB];
        #pragma unroll
        for (int b = 0; b < NB; ++b) { a0[b] = bh0; a1[b] = bh1; }

        #pragma unroll 2
        for (int k = 0; k < 128; ++k) {
            const float4 A0 = s_buf[wave][k][0];
            const float4 A1 = s_buf[wave][k][1];
            const float2 w  = sW1p[k * 64 + lane];
            a0[0] = fmaf(A0.x, w.x, a0[0]); a1[0] = fmaf(A0.x, w.y, a1[0]);
            a0[1] = fmaf(A0.y, w.x, a0[1]); a1[1] = fmaf(A0.y, w.y, a1[1]);
            a0[2] = fmaf(A0.z, w.x, a0[2]); a1[2] = fmaf(A0.z, w.y, a1[2]);
            a0[3] = fmaf(A0.w, w.x, a0[3]); a1[3] = fmaf(A0.w, w.y, a1[3]);
            a0[4] = fmaf(A1.x, w.x, a0[4]); a1[4] = fmaf(A1.x, w.y, a1[4]);
            a0[5] = fmaf(A1.y, w.x, a0[5]); a1[5] = fmaf(A1.y, w.y, a1[5]);
            a0[6] = fmaf(A1.z, w.x, a0[6]); a1[6] = fmaf(A1.z, w.y, a1[6]);
            a0[7] = fmaf(A1.w, w.x, a0[7]); a1[7] = fmaf(A1.w, w.y, a1[7]);
        }
        __builtin_amdgcn_wave_barrier();
        s_buf[wave][lane][0] = make_float4(fmaxf(a0[0], 0.f), fmaxf(a0[1], 0.f),
                                           fmaxf(a0[2], 0.f), fmaxf(a0[3], 0.f));
        s_buf[wave][lane][1] = make_float4(fmaxf(a0[4], 0.f), fmaxf(a0[5], 0.f),
                                           fmaxf(a0[6], 0.f), fmaxf(a0[7], 0.f));
        s_buf[wave][64 + lane][0] = make_float4(fmaxf(a1[0], 0.f), fmaxf(a1[1], 0.f),
                                                fmaxf(a1[2], 0.f), fmaxf(a1[3], 0.f));
        s_buf[wave][64 + lane][1] = make_float4(fmaxf(a1[4], 0.f), fmaxf(a1[5], 0.f),
                                                fmaxf(a1[6], 0.f), fmaxf(a1[7], 0.f));
        __builtin_amdgcn_wave_barrier();

        float o[NB];
        #pragma unroll
        for (int b = 0; b < NB; ++b) o[b] = bo;
        #pragma unroll 2
        for (int q2 = 0; q2 < 64; ++q2) {
            const unsigned wp = sW2p[q2 * 64 + lane];
            const float w0 = bf_lo(wp), w1 = bf_hi(wp);
            const float4 H0a = s_buf[wave][2 * q2][0];
            const float4 H0b = s_buf[wave][2 * q2][1];
            const float4 H1a = s_buf[wave][2 * q2 + 1][0];
            const float4 H1b = s_buf[wave][2 * q2 + 1][1];
            o[0] = fmaf(H0a.x, w0, o[0]); o[0] = fmaf(H1a.x, w1, o[0]);
            o[1] = fmaf(H0a.y, w0, o[1]); o[1] = fmaf(H1a.y, w1, o[1]);
            o[2] = fmaf(H0a.z, w0, o[2]); o[2] = fmaf(H1a.z, w1, o[2]);
            o[3] = fmaf(H0a.w, w0, o[3]); o[3] = fmaf(H1a.w, w1, o[3]);
            o[4] = fmaf(H0b.x, w0, o[4]); o[4] = fmaf(H1b.x, w1, o[4]);
            o[5] = fmaf(H0b.y, w0, o[5]); o[5] = fmaf(H1b.y, w1, o[5]);
            o[6] = fmaf(H0b.z, w0, o[6]); o[6] = fmaf(H1b.z, w1, o[6]);
            o[7] = fmaf(H0b.w, w0, o[7]); o[7] = fmaf(H1b.w, w1, o[7]);
        }
        #pragma unroll
        for (int b = 0; b < NB; ++b) {
            const int n = n0 + b;
            if (n < n_nodes) out[(size_t)n * D + lane] = o[b];
        }
    }
}

// ---------------------------------------------------------------------------
extern "C" void kernel_launch(void* const* d_in, const int* in_sizes, int n_in,
                              void* d_out, int out_size, void* d_ws, size_t ws_size,
                              hipStream_t stream)
{
    const float* x_node = (const float*)d_in[0];
    const float* x_edge = (const float*)d_in[1];
    const int*   eidx   = (const int*)d_in[2];
    const float* W1     = (const float*)d_in[3];
    const float* b1     = (const float*)d_in[4];
    const float* W2     = (const float*)d_in[5];
    const float* b2     = (const float*)d_in[6];
    float* out = (float*)d_out;

    const int n_nodes = in_sizes[0] / D;     // 50000
    const int n_edges = in_sizes[2] / 2;     // 800000
    const int E2 = 2 * n_edges;

    float* agg = out;   // agg lives in d_out; MLP rewrites rows in place

    // ws layout (4B words): counts[N] | ovf_cnt | pad | ovf[2E int2] |
    //                       elist[N*CAP] | nid_u16[2E] (E2/2 words)
    const size_t w_counts = (size_t)n_nodes;
    const size_t w_ovfc   = w_counts + 1;
    const size_t w_ovf    = (w_ovfc + 1 + 1) & ~(size_t)1;       // 8B align
    const size_t w_elist  = w_ovf + (size_t)E2 * 2;
    const size_t w_nid    = w_elist + (size_t)n_nodes * CAP;
    const size_t w_total  = w_nid + ((size_t)E2 + 1) / 2;
    const size_t need     = w_total * 4;
    const int u16_ok      = (n_nodes <= 65535) ? 1 : 0;

    if (ws_size >= need) {
        int*  counts  = (int*)d_ws;
        int*  ovf_cnt = (int*)d_ws + w_ovfc;
        int2* ovf     = (int2*)((int*)d_ws + w_ovf);
        int*  elist   = (int*)d_ws + w_elist;
        ush*  nid     = (ush*)((int*)d_ws + w_nid);

        // Host-side capability queries (capture-safe: no alloc/sync)
        int dev = 0; hipGetDevice(&dev);
        int coop = 0;
        hipDeviceGetAttribute(&coop, hipDeviceAttributeCooperativeLaunch, dev);
        int ncu = 0;
        hipDeviceGetAttribute(&ncu, hipDeviceAttributeMultiprocessorCount, dev);
        int nblk = 0;
        if (coop)
            hipOccupancyMaxActiveBlocksPerMultiprocessor(
                &nblk, (const void*)fused_agg, 256, 0);

        if (coop && nblk > 0 && ncu > 0) {
            // single cooperative kernel for decode+place+gather+overflow
            const int grid = ncu * nblk;
            const int*   a_eidx  = eidx;   ush*  a_nid  = nid;
            int*  a_zbase = counts;        int*  a_cnts = counts;
            int*  a_elist = elist;         int*  a_ovfc = ovf_cnt;
            int2* a_ovf   = ovf;           const float* a_xe = x_edge;
            float* a_agg  = agg;
            int a_E = n_edges, a_N = n_nodes, a_u16 = u16_ok;
            void* args[] = { (void*)&a_eidx, (void*)&a_nid, (void*)&a_zbase,
                             (void*)&a_cnts, (void*)&a_elist, (void*)&a_ovfc,
                             (void*)&a_ovf, (void*)&a_xe, (void*)&a_agg,
                             (void*)&a_E, (void*)&a_N, (void*)&a_u16 };
            hipLaunchCooperativeKernel((const void*)fused_agg,
                                       dim3(grid), dim3(256),
                                       args, 0, stream);
        } else {
            // R8 sequential fallback
            const int n_windows = (n_nodes + (1 << WIN_SHIFT) - 1) >> WIN_SHIFT;
            if (u16_ok) {
                p0_nid<<<(E2 + 255) / 256, 256, 0, stream>>>(
                    eidx, nid, counts, n_nodes + 2, n_edges);
                p1_place16<<<dim3(512, n_windows), 256, 0, stream>>>(
                    nid, counts, elist, ovf_cnt, ovf, n_edges);
            } else {
                hipMemsetAsync(counts, 0, ((size_t)n_nodes + 2) * 4, stream);
                p1_place<<<dim3(512, n_windows), 256, 0, stream>>>(
                    eidx, counts, elist, ovf_cnt, ovf, n_edges);
            }
            p2_gather<<<(n_nodes * 64 + 255) / 256, 256, 0, stream>>>(
                x_edge, counts, elist, agg, n_nodes);
            p3_ovf<<<64, 256, 0, stream>>>(x_edge, ovf_cnt, ovf, agg);
        }
    } else {
        hipMemsetAsync(agg, 0, (size_t)n_nodes * D * sizeof(float), stream);
        long long threads = (long long)n_edges * 64;
        nb_scatter<<<(int)((threads + 255) / 256), 256, 0, stream>>>(
            x_edge, eidx, agg, n_edges);
    }

    p4_mlp<<<196, MLPB, 0, stream>>>(x_node, agg, W1, b1, W2, b2, out, n_nodes);
}

// Round 10
// 246.396 us; speedup vs baseline: 2.4554x; 2.4554x over previous
//
#include <hip/hip_runtime.h>

#define D 64          // node/edge feature dim
#define HID 128       // hidden dim
#define MLPB 1024     // MLP block size (16 waves)
#define WPB 16        // waves per MLP block
#define NB 8          // nodes per wave-batch
#define CAP 96        // elist slots per node (mean degree 32; Poisson tail ~0)
#define WIN_SHIFT 12  // 4096 nodes per place-window -> ~1.5MB elist window (R6/R8-proven)

typedef unsigned short ush;

// bf16 round-to-nearest-even (finite normals)
__device__ __forceinline__ ush f2bf(float f)
{
    unsigned u = __float_as_uint(f);
    return (ush)((u + 0x7FFF + ((u >> 16) & 1)) >> 16);
}
__device__ __forceinline__ float bf_lo(unsigned p) { return __uint_as_float(p << 16); }
__device__ __forceinline__ float bf_hi(unsigned p) { return __uint_as_float(p & 0xFFFF0000u); }

// ---------------------------------------------------------------------------
// Index dtype: reference says int64, harness may deliver int32. Probe high
// words of the first 64 pairs: int64 -> all zero (ids < 50000); int32 ->
// random node ids, P(all zero) ~ (2e-5)^64 ~ 0. Deterministic.
// ---------------------------------------------------------------------------
__device__ __forceinline__ bool detect_i64(const int* __restrict__ eidx, int lane)
{
    int probe = eidx[2 * lane + 1];
    return (__ballot(probe == 0) == ~0ULL);
}

// ---------------------------------------------------------------------------
// p0_conv: PURE STREAMING (no atomics — the R5 mistake was mixing this with
// the atomic hist): decode u16 nid (3.2MB), zero counts/ovf_cnt, and convert
// x_edge f32 -> bf16 xbf (204.8MB read + 102.4MB write). xbf fits L3, making
// the gather's second touches L3-served.
// ---------------------------------------------------------------------------
__global__ __launch_bounds__(256)
void p0_conv(const int* __restrict__ eidx, ush* __restrict__ nid,
             int* __restrict__ counts, int n_zero,
             const float* __restrict__ x_edge, ushort4* __restrict__ xb4,
             int n_edges)
{
    const int tid = blockIdx.x * 256 + threadIdx.x;
    const int nth = gridDim.x * 256;
    const bool is64 = detect_i64(eidx, threadIdx.x & 63);
    const int E2 = 2 * n_edges;
    for (int t = tid; t < E2; t += nth)
        nid[t] = (ush)(is64 ? eidx[2 * (size_t)t] : eidx[t]);
    for (int t = tid; t < n_zero; t += nth) counts[t] = 0;
    const int nf4 = n_edges * 16;            // 12.8M float4s
    const float4* __restrict__ xe4 = (const float4*)x_edge;
    for (int c = tid; c < nf4; c += nth) {
        float4 v = xe4[c];
        xb4[c] = make_ushort4(f2bf(v.x), f2bf(v.y), f2bf(v.z), f2bf(v.w));
    }
}

// base-tier p0 (no conversion) — R8-proven
__global__ __launch_bounds__(256)
void p0_nid(const int* __restrict__ eidx, ush* __restrict__ nid,
            int* __restrict__ counts, int n_zero, int n_edges)
{
    const int t = blockIdx.x * 256 + threadIdx.x;
    const bool is64 = detect_i64(eidx, threadIdx.x & 63);
    const int E2 = 2 * n_edges;
    if (t < E2) nid[t] = (ush)(is64 ? eidx[2 * (size_t)t] : eidx[t]);
    if (t < n_zero) counts[t] = 0;
}

// ---------------------------------------------------------------------------
// Windowed fixed-capacity place (u16 nid input). blockIdx.y = node window;
// the window's elist range (~1.5MB) and counts stay cache-resident so a
// node's consecutive slots coalesce on few lines. Overflow -> cleanup list.
// ---------------------------------------------------------------------------
__global__ __launch_bounds__(256)
void p1_place16(const ush* __restrict__ nid, int* __restrict__ counts,
                int* __restrict__ elist, int* __restrict__ ovf_cnt,
                int2* __restrict__ ovf, int n_edges)
{
    const int lo = blockIdx.y << WIN_SHIFT;
    const int hi = lo + (1 << WIN_SHIFT);
    const int E2 = 2 * n_edges;
    const int stride = gridDim.x * 256;
    for (int t = blockIdx.x * 256 + threadIdx.x; t < E2; t += stride) {
        int idx = nid[t];
        if (idx >= lo && idx < hi) {
            int eid = (t < n_edges) ? t : t - n_edges;
            int c = atomicAdd(&counts[idx], 1);
            if (c < CAP) elist[(size_t)idx * CAP + c] = eid;
            else {
                int p = atomicAdd(ovf_cnt, 1);
                ovf[p] = make_int2(idx, eid);
            }
        }
    }
}

// int fallback (n_nodes > 65535): decodes eidx per pass.
__global__ __launch_bounds__(256)
void p1_place(const int* __restrict__ eidx, int* __restrict__ counts,
              int* __restrict__ elist, int* __restrict__ ovf_cnt,
              int2* __restrict__ ovf, int n_edges)
{
    const int lo = blockIdx.y << WIN_SHIFT;
    const int hi = lo + (1 << WIN_SHIFT);
    const int E2 = 2 * n_edges;
    const bool is64 = detect_i64(eidx, threadIdx.x & 63);
    const int stride = gridDim.x * 256;
    for (int t = blockIdx.x * 256 + threadIdx.x; t < E2; t += stride) {
        int idx = is64 ? eidx[2 * (size_t)t] : eidx[t];
        if (idx >= lo && idx < hi) {
            int eid = (t < n_edges) ? t : t - n_edges;
            int c = atomicAdd(&counts[idx], 1);
            if (c < CAP) elist[(size_t)idx * CAP + c] = eid;
            else {
                int p = atomicAdd(ovf_cnt, 1);
                ovf[p] = make_int2(idx, eid);
            }
        }
    }
}

// ---------------------------------------------------------------------------
// bf16 gather: agg[n] = sum of incident xbf rows. One wave per node.
// 8 lanes x uint4(8 bf16) cover one 128B row (2 cache lines); 8 row slots
// (lane>>3), 4x unrolled -> 32 edges in flight. f32 accumulation.
// xbf (102MB) + elist (19MB) + agg (13MB) < L3 -> re-touches L3-served.
// ---------------------------------------------------------------------------
__global__ __launch_bounds__(256)
void p2_gather_bf16(const ush* __restrict__ xbf, const int* __restrict__ counts,
                    const int* __restrict__ elist, float* __restrict__ agg,
                    int n_nodes)
{
    const int w = (blockIdx.x * 256 + threadIdx.x) >> 6;
    if (w >= n_nodes) return;
    const int lane = threadIdx.x & 63;
    const int sub = lane >> 3;       // row slot 0..7
    const int q   = lane & 7;        // uint4 index within 128B row
    const uint4* __restrict__ x4 = (const uint4*)xbf;

    int cnt = counts[w]; if (cnt > CAP) cnt = CAP;
    const int beg = w * CAP, end = beg + cnt;
    float acc[8] = {0.f, 0.f, 0.f, 0.f, 0.f, 0.f, 0.f, 0.f};

    #define ACC8(u) do {                                   \
        acc[0] += bf_lo((u).x); acc[1] += bf_hi((u).x);    \
        acc[2] += bf_lo((u).y); acc[3] += bf_hi((u).y);    \
        acc[4] += bf_lo((u).z); acc[5] += bf_hi((u).z);    \
        acc[6] += bf_lo((u).w); acc[7] += bf_hi((u).w);    \
    } while (0)

    int i = beg + sub;
    for (; i + 24 < end; i += 32) {
        int e0 = elist[i];
        int e1 = elist[i + 8];
        int e2 = elist[i + 16];
        int e3 = elist[i + 24];
        uint4 u0 = x4[(size_t)e0 * 8 + q];
        uint4 u1 = x4[(size_t)e1 * 8 + q];
        uint4 u2 = x4[(size_t)e2 * 8 + q];
        uint4 u3 = x4[(size_t)e3 * 8 + q];
        ACC8(u0); ACC8(u1); ACC8(u2); ACC8(u3);
    }
    for (; i < end; i += 8) {
        uint4 u = x4[(size_t)elist[i] * 8 + q];
        ACC8(u);
    }
    #undef ACC8

    // reduce across the 8 row slots (lane bits 3,4,5)
    #pragma unroll
    for (int m = 8; m < 64; m <<= 1) {
        #pragma unroll
        for (int r = 0; r < 8; ++r) acc[r] += __shfl_xor(acc[r], m);
    }
    if (sub == 0) {
        float4* ap = (float4*)(agg + (size_t)w * D + q * 8);
        ap[0] = make_float4(acc[0], acc[1], acc[2], acc[3]);
        ap[1] = make_float4(acc[4], acc[5], acc[6], acc[7]);
    }
}

// f32 gather (base tier) — R8-proven
__global__ __launch_bounds__(256)
void p2_gather(const float* __restrict__ x_edge, const int* __restrict__ counts,
               const int* __restrict__ elist, float* __restrict__ agg, int n_nodes)
{
    const int w = (blockIdx.x * 256 + threadIdx.x) >> 6;
    if (w >= n_nodes) return;
    const int lane = threadIdx.x & 63;
    const int sub = lane >> 4;
    const int q   = lane & 15;
    const float4* __restrict__ xe4 = (const float4*)x_edge;

    int cnt = counts[w]; if (cnt > CAP) cnt = CAP;
    const int beg = w * CAP, end = beg + cnt;
    float4 acc = make_float4(0.f, 0.f, 0.f, 0.f);

    int i = beg + sub;
    for (; i + 12 < end; i += 16) {
        int e0 = elist[i];
        int e1 = elist[i + 4];
        int e2 = elist[i + 8];
        int e3 = elist[i + 12];
        float4 v0 = xe4[(size_t)e0 * 16 + q];
        float4 v1 = xe4[(size_t)e1 * 16 + q];
        float4 v2 = xe4[(size_t)e2 * 16 + q];
        float4 v3 = xe4[(size_t)e3 * 16 + q];
        acc.x += (v0.x + v1.x) + (v2.x + v3.x);
        acc.y += (v0.y + v1.y) + (v2.y + v3.y);
        acc.z += (v0.z + v1.z) + (v2.z + v3.z);
        acc.w += (v0.w + v1.w) + (v2.w + v3.w);
    }
    for (; i < end; i += 4) {
        float4 v = xe4[(size_t)elist[i] * 16 + q];
        acc.x += v.x; acc.y += v.y; acc.z += v.z; acc.w += v.w;
    }
    #pragma unroll
    for (int m = 16; m < 64; m <<= 1) {
        acc.x += __shfl_xor(acc.x, m);
        acc.y += __shfl_xor(acc.y, m);
        acc.z += __shfl_xor(acc.z, m);
        acc.w += __shfl_xor(acc.w, m);
    }
    if (sub == 0)
        ((float4*)agg)[(size_t)w * 16 + q] = acc;
}

// ---------------------------------------------------------------------------
// Overflow cleanup: usually 0 entries. One wave per entry, atomic add of the
// f32 edge row into agg. Runs after the gather (which overwrites agg rows).
// ---------------------------------------------------------------------------
__global__ __launch_bounds__(256)
void p3_ovf(const float* __restrict__ x_edge, const int* __restrict__ ovf_cnt,
            const int2* __restrict__ ovf, float* __restrict__ agg)
{
    const int n = *ovf_cnt;
    const int lane = threadIdx.x & 63;
    const int wv = (blockIdx.x * 256 + threadIdx.x) >> 6;
    const int nw = gridDim.x * 4;
    for (int i = wv; i < n; i += nw) {
        int2 p = ovf[i];
        float v = x_edge[(size_t)p.y * D + lane];
        unsafeAtomicAdd(&agg[(size_t)p.x * D + lane], v);
    }
}

// ---------- fallback atomic scatter (tiny ws) ------------------------------
__global__ __launch_bounds__(256)
void nb_scatter(const float* __restrict__ x_edge, const int* __restrict__ eidx,
                float* __restrict__ agg, int n_edges)
{
    long long t = (long long)blockIdx.x * 256 + threadIdx.x;
    int e = (int)(t >> 6);
    if (e >= n_edges) return;
    int d = (int)(t & 63);
    bool is64 = detect_i64(eidx, threadIdx.x & 63);
    int s, dd;
    if (is64) {
        s  = eidx[2 * (size_t)e];
        dd = eidx[2 * ((size_t)n_edges + (size_t)e)];
    } else {
        s  = eidx[e];
        dd = eidx[n_edges + e];
    }
    float v = x_edge[(size_t)e * D + d];
    unsafeAtomicAdd(&agg[(size_t)s * D + d], v);
    unsafeAtomicAdd(&agg[(size_t)dd * D + d], v);
}

// ---------------------------------------------------------------------------
// MLP: out[n] = relu(concat(x_node[n], agg[n]) @ W1 + b1) @ W2 + b2
// NB=8 nodes per wave-batch; W1 as float2 pairs (b64 -> 16 FMAs); W2 bf16-
// packed (b32 -> 32 FMAs); s_buf inputs/hidden overlaid. LDS ~145KB.
// agg read from d_out, out written in place (row n touched only by its wave).
// ---------------------------------------------------------------------------
__global__ __launch_bounds__(MLPB, 1)
void p4_mlp(const float* __restrict__ x_node, const float* __restrict__ agg,
            const float* __restrict__ W1, const float* __restrict__ b1,
            const float* __restrict__ W2, const float* __restrict__ b2,
            float* __restrict__ out, int n_nodes)
{
    __shared__ float2   sW1p[HID * 64];        // 64 KB
    __shared__ unsigned sW2p[64 * 64];         // 16 KB
    __shared__ float    sb1[HID];
    __shared__ float    sb2[D];
    __shared__ float4   s_buf[WPB][128][2];    // 64 KB

    {
        for (int t = threadIdx.x; t < HID * 64; t += MLPB) {
            int k = t >> 6, j = t & 63;
            sW1p[t] = make_float2(W1[k * HID + j], W1[k * HID + 64 + j]);
        }
        for (int t = threadIdx.x; t < 64 * 64; t += MLPB) {
            int q = t >> 6, j = t & 63;
            unsigned lo = f2bf(W2[(2 * q) * D + j]);
            unsigned hi = f2bf(W2[(2 * q + 1) * D + j]);
            sW2p[t] = lo | (hi << 16);
        }
        if (threadIdx.x < 128) sb1[threadIdx.x] = b1[threadIdx.x];
        else if (threadIdx.x < 192) sb2[threadIdx.x - 128] = b2[threadIdx.x - 128];
    }
    __syncthreads();

    const int wave = threadIdx.x >> 6;
    const int lane = threadIdx.x & 63;
    const int group = blockIdx.x * WPB + wave;
    const int ngroups = gridDim.x * WPB;
    const int nbatches = (n_nodes + NB - 1) / NB;

    const float bh0 = sb1[lane], bh1 = sb1[64 + lane];
    const float bo  = sb2[lane];

    for (int g = group; g < nbatches; g += ngroups) {
        const int n0 = g * NB;

        float vx[NB], va[NB];
        #pragma unroll
        for (int b = 0; b < NB; ++b) {
            const int n = n0 + b;
            const bool ok = (n < n_nodes);
            vx[b] = ok ? x_node[(size_t)n * D + lane] : 0.f;
            va[b] = ok ? agg[(size_t)n * D + lane] : 0.f;
        }
        s_buf[wave][lane][0]      = make_float4(vx[0], vx[1], vx[2], vx[3]);
        s_buf[wave][lane][1]      = make_float4(vx[4], vx[5], vx[6], vx[7]);
        s_buf[wave][64 + lane][0] = make_float4(va[0], va[1], va[2], va[3]);
        s_buf[wave][64 + lane][1] = make_float4(va[4], va[5], va[6], va[7]);
        __builtin_amdgcn_wave_barrier();

        float a0[NB], a1[NB];
        #pragma unroll
        for (int b = 0; b < NB; ++b) { a0[b] = bh0; a1[b] = bh1; }

        #pragma unroll 2
        for (int k = 0; k < 128; ++k) {
            const float4 A0 = s_buf[wave][k][0];
            const float4 A1 = s_buf[wave][k][1];
            const float2 w  = sW1p[k * 64 + lane];
            a0[0] = fmaf(A0.x, w.x, a0[0]); a1[0] = fmaf(A0.x, w.y, a1[0]);
            a0[1] = fmaf(A0.y, w.x, a0[1]); a1[1] = fmaf(A0.y, w.y, a1[1]);
            a0[2] = fmaf(A0.z, w.x, a0[2]); a1[2] = fmaf(A0.z, w.y, a1[2]);
            a0[3] = fmaf(A0.w, w.x, a0[3]); a1[3] = fmaf(A0.w, w.y, a1[3]);
            a0[4] = fmaf(A1.x, w.x, a0[4]); a1[4] = fmaf(A1.x, w.y, a1[4]);
            a0[5] = fmaf(A1.y, w.x, a0[5]); a1[5] = fmaf(A1.y, w.y, a1[5]);
            a0[6] = fmaf(A1.z, w.x, a0[6]); a1[6] = fmaf(A1.z, w.y, a1[6]);
            a0[7] = fmaf(A1.w, w.x, a0[7]); a1[7] = fmaf(A1.w, w.y, a1[7]);
        }
        __builtin_amdgcn_wave_barrier();
        s_buf[wave][lane][0] = make_float4(fmaxf(a0[0], 0.f), fmaxf(a0[1], 0.f),
                                           fmaxf(a0[2], 0.f), fmaxf(a0[3], 0.f));
        s_buf[wave][lane][1] = make_float4(fmaxf(a0[4], 0.f), fmaxf(a0[5], 0.f),
                                           fmaxf(a0[6], 0.f), fmaxf(a0[7], 0.f));
        s_buf[wave][64 + lane][0] = make_float4(fmaxf(a1[0], 0.f), fmaxf(a1[1], 0.f),
                                                fmaxf(a1[2], 0.f), fmaxf(a1[3], 0.f));
        s_buf[wave][64 + lane][1] = make_float4(fmaxf(a1[4], 0.f), fmaxf(a1[5], 0.f),
                                                fmaxf(a1[6], 0.f), fmaxf(a1[7], 0.f));
        __builtin_amdgcn_wave_barrier();

        float o[NB];
        #pragma unroll
        for (int b = 0; b < NB; ++b) o[b] = bo;
        #pragma unroll 2
        for (int q2 = 0; q2 < 64; ++q2) {
            const unsigned wp = sW2p[q2 * 64 + lane];
            const float w0 = bf_lo(wp), w1 = bf_hi(wp);
            const float4 H0a = s_buf[wave][2 * q2][0];
            const float4 H0b = s_buf[wave][2 * q2][1];
            const float4 H1a = s_buf[wave][2 * q2 + 1][0];
            const float4 H1b = s_buf[wave][2 * q2 + 1][1];
            o[0] = fmaf(H0a.x, w0, o[0]); o[0] = fmaf(H1a.x, w1, o[0]);
            o[1] = fmaf(H0a.y, w0, o[1]); o[1] = fmaf(H1a.y, w1, o[1]);
            o[2] = fmaf(H0a.z, w0, o[2]); o[2] = fmaf(H1a.z, w1, o[2]);
            o[3] = fmaf(H0a.w, w0, o[3]); o[3] = fmaf(H1a.w, w1, o[3]);
            o[4] = fmaf(H0b.x, w0, o[4]); o[4] = fmaf(H1b.x, w1, o[4]);
            o[5] = fmaf(H0b.y, w0, o[5]); o[5] = fmaf(H1b.y, w1, o[5]);
            o[6] = fmaf(H0b.z, w0, o[6]); o[6] = fmaf(H1b.z, w1, o[6]);
            o[7] = fmaf(H0b.w, w0, o[7]); o[7] = fmaf(H1b.w, w1, o[7]);
        }
        #pragma unroll
        for (int b = 0; b < NB; ++b) {
            const int n = n0 + b;
            if (n < n_nodes) out[(size_t)n * D + lane] = o[b];
        }
    }
}

// ---------------------------------------------------------------------------
extern "C" void kernel_launch(void* const* d_in, const int* in_sizes, int n_in,
                              void* d_out, int out_size, void* d_ws, size_t ws_size,
                              hipStream_t stream)
{
    const float* x_node = (const float*)d_in[0];
    const float* x_edge = (const float*)d_in[1];
    const int*   eidx   = (const int*)d_in[2];
    const float* W1     = (const float*)d_in[3];
    const float* b1     = (const float*)d_in[4];
    const float* W2     = (const float*)d_in[5];
    const float* b2     = (const float*)d_in[6];
    float* out = (float*)d_out;

    const int n_nodes = in_sizes[0] / D;     // 50000
    const int n_edges = in_sizes[2] / 2;     // 800000
    const int E2 = 2 * n_edges;

    float* agg = out;   // agg lives in d_out; MLP rewrites rows in place

    // ws layout (4B words): counts[N] | ovf_cnt | pad | ovf[2E int2] |
    //   elist[N*CAP] | nid_u16[2E] | (16B align) xbf[E*64 ush]
    const size_t w_counts = (size_t)n_nodes;
    const size_t w_ovfc   = w_counts + 1;
    const size_t w_ovf    = (w_ovfc + 1 + 1) & ~(size_t)1;       // 8B align
    const size_t w_elist  = w_ovf + (size_t)E2 * 2;
    const size_t w_nid    = w_elist + (size_t)n_nodes * CAP;
    const size_t w_nidend = w_nid + ((size_t)E2 + 1) / 2;
    const size_t w_xbf    = (w_nidend + 3) & ~(size_t)3;         // 16B align
    const size_t w_full   = w_xbf + (size_t)n_edges * 32;        // E*64 ush
    const size_t need_base = w_nidend * 4;
    const size_t need_full = w_full * 4;
    const int u16_ok       = (n_nodes <= 65535) ? 1 : 0;

    if (ws_size >= need_base) {
        int*  counts  = (int*)d_ws;
        int*  ovf_cnt = (int*)d_ws + w_ovfc;
        int2* ovf     = (int2*)((int*)d_ws + w_ovf);
        int*  elist   = (int*)d_ws + w_elist;
        ush*  nid     = (ush*)((int*)d_ws + w_nid);
        ush*  xbf     = (ush*)((int*)d_ws + w_xbf);

        const int n_windows = (n_nodes + (1 << WIN_SHIFT) - 1) >> WIN_SHIFT;  // 13
        const int bf16_tier = (u16_ok && ws_size >= need_full) ? 1 : 0;

        if (bf16_tier) {
            // streaming decode + zero + f32->bf16 conversion (no atomics)
            p0_conv<<<2048, 256, 0, stream>>>(
                eidx, nid, counts, n_nodes + 2, x_edge, (ushort4*)xbf, n_edges);
            p1_place16<<<dim3(512, n_windows), 256, 0, stream>>>(
                nid, counts, elist, ovf_cnt, ovf, n_edges);
            p2_gather_bf16<<<(n_nodes * 64 + 255) / 256, 256, 0, stream>>>(
                xbf, counts, elist, agg, n_nodes);
        } else if (u16_ok) {
            p0_nid<<<(E2 + 255) / 256, 256, 0, stream>>>(
                eidx, nid, counts, n_nodes + 2, n_edges);
            p1_place16<<<dim3(512, n_windows), 256, 0, stream>>>(
                nid, counts, elist, ovf_cnt, ovf, n_edges);
            p2_gather<<<(n_nodes * 64 + 255) / 256, 256, 0, stream>>>(
                x_edge, counts, elist, agg, n_nodes);
        } else {
            hipMemsetAsync(counts, 0, ((size_t)n_nodes + 2) * 4, stream);
            p1_place<<<dim3(512, n_windows), 256, 0, stream>>>(
                eidx, counts, elist, ovf_cnt, ovf, n_edges);
            p2_gather<<<(n_nodes * 64 + 255) / 256, 256, 0, stream>>>(
                x_edge, counts, elist, agg, n_nodes);
        }

        p3_ovf<<<64, 256, 0, stream>>>(x_edge, ovf_cnt, ovf, agg);
    } else {
        hipMemsetAsync(agg, 0, (size_t)n_nodes * D * sizeof(float), stream);
        long long threads = (long long)n_edges * 64;
        nb_scatter<<<(int)((threads + 255) / 256), 256, 0, stream>>>(
            x_edge, eidx, agg, n_edges);
    }

    p4_mlp<<<196, MLPB, 0, stream>>>(x_node, agg, W1, b1, W2, b2, out, n_nodes);
}

// Round 11
// 199.887 us; speedup vs baseline: 3.0267x; 1.2327x over previous
//
#include <hip/hip_runtime.h>

#define D 64          // node/edge feature dim
#define HID 128       // hidden dim
#define MLPB 1024     // MLP block size (16 waves)
#define WPB 16        // waves per MLP block
#define NB 8          // nodes per wave-batch
#define CAP 96        // elist slots per node (mean degree 32; Poisson tail ~0)
#define WIN_SHIFT 12  // 4096 nodes per place-window -> ~1.5MB elist window (R6/R8-proven)

typedef unsigned short ush;

// bf16 round-to-nearest-even (finite normals)
__device__ __forceinline__ ush f2bf(float f)
{
    unsigned u = __float_as_uint(f);
    return (ush)((u + 0x7FFF + ((u >> 16) & 1)) >> 16);
}
__device__ __forceinline__ float bf_lo(unsigned p) { return __uint_as_float(p << 16); }
__device__ __forceinline__ float bf_hi(unsigned p) { return __uint_as_float(p & 0xFFFF0000u); }

// ---------------------------------------------------------------------------
// Index dtype: reference says int64, harness may deliver int32. Probe high
// words of the first 64 pairs: int64 -> all zero (ids < 50000); int32 ->
// random node ids, P(all zero) ~ (2e-5)^64 ~ 0. Deterministic.
// ---------------------------------------------------------------------------
__device__ __forceinline__ bool detect_i64(const int* __restrict__ eidx, int lane)
{
    int probe = eidx[2 * lane + 1];
    return (__ballot(probe == 0) == ~0ULL);
}

// ---------------------------------------------------------------------------
// p0: decode edge_index once into u16 node ids (3.2MB, cache-resident for the
// place sweeps) and zero counts+ovf_cnt (folds the memset launch away).
// Entry t in [0,2E): t<E -> src of edge t; t>=E -> dst of edge t-E.
// ---------------------------------------------------------------------------
__global__ __launch_bounds__(256)
void p0_nid(const int* __restrict__ eidx, ush* __restrict__ nid,
            int* __restrict__ counts, int n_zero, int n_edges)
{
    const int t = blockIdx.x * 256 + threadIdx.x;
    const bool is64 = detect_i64(eidx, threadIdx.x & 63);
    const int E2 = 2 * n_edges;
    if (t < E2) nid[t] = (ush)(is64 ? eidx[2 * (size_t)t] : eidx[t]);
    if (t < n_zero) counts[t] = 0;
}

// ---------------------------------------------------------------------------
// Windowed fixed-capacity place (u16 nid input). blockIdx.y = node window;
// only in-window entries are committed by that y-slice, so the window's elist
// range (~1.5MB) and counts stay cache-resident and a node's consecutive
// slots coalesce on few lines. Overflow (c >= CAP) goes to a cleanup list.
// ---------------------------------------------------------------------------
__global__ __launch_bounds__(256)
void p1_place16(const ush* __restrict__ nid, int* __restrict__ counts,
                int* __restrict__ elist, int* __restrict__ ovf_cnt,
                int2* __restrict__ ovf, int n_edges)
{
    const int lo = blockIdx.y << WIN_SHIFT;
    const int hi = lo + (1 << WIN_SHIFT);
    const int E2 = 2 * n_edges;
    const int stride = gridDim.x * 256;
    for (int t = blockIdx.x * 256 + threadIdx.x; t < E2; t += stride) {
        int idx = nid[t];
        if (idx >= lo && idx < hi) {
            int eid = (t < n_edges) ? t : t - n_edges;
            int c = atomicAdd(&counts[idx], 1);
            if (c < CAP) elist[(size_t)idx * CAP + c] = eid;
            else {
                int p = atomicAdd(ovf_cnt, 1);
                ovf[p] = make_int2(idx, eid);
            }
        }
    }
}

// int fallback (n_nodes > 65535): identical logic, decodes eidx per pass.
__global__ __launch_bounds__(256)
void p1_place(const int* __restrict__ eidx, int* __restrict__ counts,
              int* __restrict__ elist, int* __restrict__ ovf_cnt,
              int2* __restrict__ ovf, int n_edges)
{
    const int lo = blockIdx.y << WIN_SHIFT;
    const int hi = lo + (1 << WIN_SHIFT);
    const int E2 = 2 * n_edges;
    const bool is64 = detect_i64(eidx, threadIdx.x & 63);
    const int stride = gridDim.x * 256;
    for (int t = blockIdx.x * 256 + threadIdx.x; t < E2; t += stride) {
        int idx = is64 ? eidx[2 * (size_t)t] : eidx[t];
        if (idx >= lo && idx < hi) {
            int eid = (t < n_edges) ? t : t - n_edges;
            int c = atomicAdd(&counts[idx], 1);
            if (c < CAP) elist[(size_t)idx * CAP + c] = eid;
            else {
                int p = atomicAdd(ovf_cnt, 1);
                ovf[p] = make_int2(idx, eid);
            }
        }
    }
}

// ---------------------------------------------------------------------------
// Gather: agg[n] = sum over incident edges of x_edge[e]. One wave per node.
// 16 lanes x float4 cover one 256B row; 4 row slots (lane>>4), 4x unrolled
// -> 16 edges in flight. No LDS, full occupancy. At the measured random-
// request floor (~3.9 TB/s effective): ILP-8 (R7) and bf16 (R10) both ~0.
// ---------------------------------------------------------------------------
__global__ __launch_bounds__(256)
void p2_gather(const float* __restrict__ x_edge, const int* __restrict__ counts,
               const int* __restrict__ elist, float* __restrict__ agg, int n_nodes)
{
    const int w = (blockIdx.x * 256 + threadIdx.x) >> 6;
    if (w >= n_nodes) return;
    const int lane = threadIdx.x & 63;
    const int sub = lane >> 4;       // row slot 0..3
    const int q   = lane & 15;       // float4 index within row
    const float4* __restrict__ xe4 = (const float4*)x_edge;

    int cnt = counts[w]; if (cnt > CAP) cnt = CAP;
    const int beg = w * CAP, end = beg + cnt;
    float4 acc = make_float4(0.f, 0.f, 0.f, 0.f);

    int i = beg + sub;
    for (; i + 12 < end; i += 16) {
        int e0 = elist[i];
        int e1 = elist[i + 4];
        int e2 = elist[i + 8];
        int e3 = elist[i + 12];
        float4 v0 = xe4[(size_t)e0 * 16 + q];
        float4 v1 = xe4[(size_t)e1 * 16 + q];
        float4 v2 = xe4[(size_t)e2 * 16 + q];
        float4 v3 = xe4[(size_t)e3 * 16 + q];
        acc.x += (v0.x + v1.x) + (v2.x + v3.x);
        acc.y += (v0.y + v1.y) + (v2.y + v3.y);
        acc.z += (v0.z + v1.z) + (v2.z + v3.z);
        acc.w += (v0.w + v1.w) + (v2.w + v3.w);
    }
    for (; i < end; i += 4) {
        float4 v = xe4[(size_t)elist[i] * 16 + q];
        acc.x += v.x; acc.y += v.y; acc.z += v.z; acc.w += v.w;
    }

    // reduce across the 4 row slots (lane bits 4,5)
    #pragma unroll
    for (int m = 16; m < 64; m <<= 1) {
        acc.x += __shfl_xor(acc.x, m);
        acc.y += __shfl_xor(acc.y, m);
        acc.z += __shfl_xor(acc.z, m);
        acc.w += __shfl_xor(acc.w, m);
    }
    if (sub == 0)
        ((float4*)agg)[(size_t)w * 16 + q] = acc;
}

// ---------------------------------------------------------------------------
// Overflow cleanup: usually 0 entries. One wave per entry, atomic add of the
// edge row into agg. Runs after p2_gather (which overwrites agg rows).
// ---------------------------------------------------------------------------
__global__ __launch_bounds__(256)
void p3_ovf(const float* __restrict__ x_edge, const int* __restrict__ ovf_cnt,
            const int2* __restrict__ ovf, float* __restrict__ agg)
{
    const int n = *ovf_cnt;
    const int lane = threadIdx.x & 63;
    const int wv = (blockIdx.x * 256 + threadIdx.x) >> 6;
    const int nw = gridDim.x * 4;
    for (int i = wv; i < n; i += nw) {
        int2 p = ovf[i];
        float v = x_edge[(size_t)p.y * D + lane];
        unsafeAtomicAdd(&agg[(size_t)p.x * D + lane], v);
    }
}

// ---------- fallback atomic scatter (tiny ws) ------------------------------
__global__ __launch_bounds__(256)
void nb_scatter(const float* __restrict__ x_edge, const int* __restrict__ eidx,
                float* __restrict__ agg, int n_edges)
{
    long long t = (long long)blockIdx.x * 256 + threadIdx.x;
    int e = (int)(t >> 6);
    if (e >= n_edges) return;
    int d = (int)(t & 63);
    bool is64 = detect_i64(eidx, threadIdx.x & 63);
    int s, dd;
    if (is64) {
        s  = eidx[2 * (size_t)e];
        dd = eidx[2 * ((size_t)n_edges + (size_t)e)];
    } else {
        s  = eidx[e];
        dd = eidx[n_edges + e];
    }
    float v = x_edge[(size_t)e * D + d];
    unsafeAtomicAdd(&agg[(size_t)s * D + d], v);
    unsafeAtomicAdd(&agg[(size_t)dd * D + d], v);
}

// ---------------------------------------------------------------------------
// MLP: out[n] = relu(concat(x_node[n], agg[n]) @ W1 + b1) @ W2 + b2
// NB=8 nodes per wave-batch. W1 staged as float2{W1[k][j],W1[k][j+64]} (one
// b64 feeds 16 FMAs); W2 staged bf16-packed (one b32 feeds 32 FMAs). s_buf
// holds inputs then hidden (overlaid). LDS ~145KB -> 1 block/CU, 16 waves.
// agg read from d_out, out written in place (row n touched only by its wave).
// ---------------------------------------------------------------------------
__global__ __launch_bounds__(MLPB, 1)
void p4_mlp(const float* __restrict__ x_node, const float* __restrict__ agg,
            const float* __restrict__ W1, const float* __restrict__ b1,
            const float* __restrict__ W2, const float* __restrict__ b2,
            float* __restrict__ out, int n_nodes)
{
    __shared__ float2   sW1p[HID * 64];        // 64 KB
    __shared__ unsigned sW2p[64 * 64];         // 16 KB
    __shared__ float    sb1[HID];
    __shared__ float    sb2[D];
    __shared__ float4   s_buf[WPB][128][2];    // 64 KB

    {
        for (int t = threadIdx.x; t < HID * 64; t += MLPB) {
            int k = t >> 6, j = t & 63;
            sW1p[t] = make_float2(W1[k * HID + j], W1[k * HID + 64 + j]);
        }
        for (int t = threadIdx.x; t < 64 * 64; t += MLPB) {
            int q = t >> 6, j = t & 63;
            unsigned lo = f2bf(W2[(2 * q) * D + j]);
            unsigned hi = f2bf(W2[(2 * q + 1) * D + j]);
            sW2p[t] = lo | (hi << 16);
        }
        if (threadIdx.x < 128) sb1[threadIdx.x] = b1[threadIdx.x];
        else if (threadIdx.x < 192) sb2[threadIdx.x - 128] = b2[threadIdx.x - 128];
    }
    __syncthreads();

    const int wave = threadIdx.x >> 6;
    const int lane = threadIdx.x & 63;
    const int group = blockIdx.x * WPB + wave;
    const int ngroups = gridDim.x * WPB;
    const int nbatches = (n_nodes + NB - 1) / NB;

    const float bh0 = sb1[lane], bh1 = sb1[64 + lane];
    const float bo  = sb2[lane];

    for (int g = group; g < nbatches; g += ngroups) {
        const int n0 = g * NB;

        float vx[NB], va[NB];
        #pragma unroll
        for (int b = 0; b < NB; ++b) {
            const int n = n0 + b;
            const bool ok = (n < n_nodes);
            vx[b] = ok ? x_node[(size_t)n * D + lane] : 0.f;
            va[b] = ok ? agg[(size_t)n * D + lane] : 0.f;
        }
        s_buf[wave][lane][0]      = make_float4(vx[0], vx[1], vx[2], vx[3]);
        s_buf[wave][lane][1]      = make_float4(vx[4], vx[5], vx[6], vx[7]);
        s_buf[wave][64 + lane][0] = make_float4(va[0], va[1], va[2], va[3]);
        s_buf[wave][64 + lane][1] = make_float4(va[4], va[5], va[6], va[7]);
        __builtin_amdgcn_wave_barrier();

        float a0[NB], a1[NB];
        #pragma unroll
        for (int b = 0; b < NB; ++b) { a0[b] = bh0; a1[b] = bh1; }

        #pragma unroll 2
        for (int k = 0; k < 128; ++k) {
            const float4 A0 = s_buf[wave][k][0];
            const float4 A1 = s_buf[wave][k][1];
            const float2 w  = sW1p[k * 64 + lane];
            a0[0] = fmaf(A0.x, w.x, a0[0]); a1[0] = fmaf(A0.x, w.y, a1[0]);
            a0[1] = fmaf(A0.y, w.x, a0[1]); a1[1] = fmaf(A0.y, w.y, a1[1]);
            a0[2] = fmaf(A0.z, w.x, a0[2]); a1[2] = fmaf(A0.z, w.y, a1[2]);
            a0[3] = fmaf(A0.w, w.x, a0[3]); a1[3] = fmaf(A0.w, w.y, a1[3]);
            a0[4] = fmaf(A1.x, w.x, a0[4]); a1[4] = fmaf(A1.x, w.y, a1[4]);
            a0[5] = fmaf(A1.y, w.x, a0[5]); a1[5] = fmaf(A1.y, w.y, a1[5]);
            a0[6] = fmaf(A1.z, w.x, a0[6]); a1[6] = fmaf(A1.z, w.y, a1[6]);
            a0[7] = fmaf(A1.w, w.x, a0[7]); a1[7] = fmaf(A1.w, w.y, a1[7]);
        }
        __builtin_amdgcn_wave_barrier();
        s_buf[wave][lane][0] = make_float4(fmaxf(a0[0], 0.f), fmaxf(a0[1], 0.f),
                                           fmaxf(a0[2], 0.f), fmaxf(a0[3], 0.f));
        s_buf[wave][lane][1] = make_float4(fmaxf(a0[4], 0.f), fmaxf(a0[5], 0.f),
                                           fmaxf(a0[6], 0.f), fmaxf(a0[7], 0.f));
        s_buf[wave][64 + lane][0] = make_float4(fmaxf(a1[0], 0.f), fmaxf(a1[1], 0.f),
                                                fmaxf(a1[2], 0.f), fmaxf(a1[3], 0.f));
        s_buf[wave][64 + lane][1] = make_float4(fmaxf(a1[4], 0.f), fmaxf(a1[5], 0.f),
                                                fmaxf(a1[6], 0.f), fmaxf(a1[7], 0.f));
        __builtin_amdgcn_wave_barrier();

        float o[NB];
        #pragma unroll
        for (int b = 0; b < NB; ++b) o[b] = bo;
        #pragma unroll 2
        for (int q2 = 0; q2 < 64; ++q2) {
            const unsigned wp = sW2p[q2 * 64 + lane];
            const float w0 = bf_lo(wp), w1 = bf_hi(wp);
            const float4 H0a = s_buf[wave][2 * q2][0];
            const float4 H0b = s_buf[wave][2 * q2][1];
            const float4 H1a = s_buf[wave][2 * q2 + 1][0];
            const float4 H1b = s_buf[wave][2 * q2 + 1][1];
            o[0] = fmaf(H0a.x, w0, o[0]); o[0] = fmaf(H1a.x, w1, o[0]);
            o[1] = fmaf(H0a.y, w0, o[1]); o[1] = fmaf(H1a.y, w1, o[1]);
            o[2] = fmaf(H0a.z, w0, o[2]); o[2] = fmaf(H1a.z, w1, o[2]);
            o[3] = fmaf(H0a.w, w0, o[3]); o[3] = fmaf(H1a.w, w1, o[3]);
            o[4] = fmaf(H0b.x, w0, o[4]); o[4] = fmaf(H1b.x, w1, o[4]);
            o[5] = fmaf(H0b.y, w0, o[5]); o[5] = fmaf(H1b.y, w1, o[5]);
            o[6] = fmaf(H0b.z, w0, o[6]); o[6] = fmaf(H1b.z, w1, o[6]);
            o[7] = fmaf(H0b.w, w0, o[7]); o[7] = fmaf(H1b.w, w1, o[7]);
        }
        #pragma unroll
        for (int b = 0; b < NB; ++b) {
            const int n = n0 + b;
            if (n < n_nodes) out[(size_t)n * D + lane] = o[b];
        }
    }
}

// ---------------------------------------------------------------------------
extern "C" void kernel_launch(void* const* d_in, const int* in_sizes, int n_in,
                              void* d_out, int out_size, void* d_ws, size_t ws_size,
                              hipStream_t stream)
{
    const float* x_node = (const float*)d_in[0];
    const float* x_edge = (const float*)d_in[1];
    const int*   eidx   = (const int*)d_in[2];
    const float* W1     = (const float*)d_in[3];
    const float* b1     = (const float*)d_in[4];
    const float* W2     = (const float*)d_in[5];
    const float* b2     = (const float*)d_in[6];
    float* out = (float*)d_out;

    const int n_nodes = in_sizes[0] / D;     // 50000
    const int n_edges = in_sizes[2] / 2;     // 800000
    const int E2 = 2 * n_edges;

    float* agg = out;   // agg lives in d_out; MLP rewrites rows in place

    // ws layout (4B words): counts[N] | ovf_cnt | pad | ovf[2E int2] |
    //                       elist[N*CAP] | nid_u16[2E] (E2/2 words)
    const size_t w_counts = (size_t)n_nodes;
    const size_t w_ovfc   = w_counts + 1;
    const size_t w_ovf    = (w_ovfc + 1 + 1) & ~(size_t)1;       // 8B align
    const size_t w_elist  = w_ovf + (size_t)E2 * 2;
    const size_t w_nid    = w_elist + (size_t)n_nodes * CAP;
    const size_t w_total  = w_nid + ((size_t)E2 + 1) / 2;
    const size_t need     = w_total * 4;
    const bool u16_ok     = (n_nodes <= 65535);

    if (ws_size >= need) {
        int*  counts  = (int*)d_ws;
        int*  ovf_cnt = (int*)d_ws + w_ovfc;
        int2* ovf     = (int2*)((int*)d_ws + w_ovf);
        int*  elist   = (int*)d_ws + w_elist;
        ush*  nid     = (ush*)((int*)d_ws + w_nid);

        const int n_windows = (n_nodes + (1 << WIN_SHIFT) - 1) >> WIN_SHIFT;  // 13

        if (u16_ok) {
            // decode nid (u16) + zero counts/ovf_cnt in one streaming kernel
            p0_nid<<<(E2 + 255) / 256, 256, 0, stream>>>(
                eidx, nid, counts, n_nodes + 2, n_edges);
            p1_place16<<<dim3(512, n_windows), 256, 0, stream>>>(
                nid, counts, elist, ovf_cnt, ovf, n_edges);
        } else {
            hipMemsetAsync(counts, 0, ((size_t)n_nodes + 2) * 4, stream);
            p1_place<<<dim3(512, n_windows), 256, 0, stream>>>(
                eidx, counts, elist, ovf_cnt, ovf, n_edges);
        }

        p2_gather<<<(n_nodes * 64 + 255) / 256, 256, 0, stream>>>(
            x_edge, counts, elist, agg, n_nodes);

        p3_ovf<<<64, 256, 0, stream>>>(x_edge, ovf_cnt, ovf, agg);
    } else {
        hipMemsetAsync(agg, 0, (size_t)n_nodes * D * sizeof(float), stream);
        long long threads = (long long)n_edges * 64;
        nb_scatter<<<(int)((threads + 255) / 256), 256, 0, stream>>>(
            x_edge, eidx, agg, n_edges);
    }

    p4_mlp<<<196, MLPB, 0, stream>>>(x_node, agg, W1, b1, W2, b2, out, n_nodes);
}